// Round 5
// baseline (1071.600 us; speedup 1.0000x reference)
//
#include <hip/hip_runtime.h>
#include <stdint.h>

typedef unsigned short u16;
typedef unsigned int u32;
typedef __attribute__((ext_vector_type(8))) short s16x8;
typedef __attribute__((ext_vector_type(4))) float f32x4;

#define P_ 256
#define L_ 64
#define IDIM 512
#define H_ 1024
#define PH (P_ * H_)

__device__ __forceinline__ u16 f2bf(float f){union{float f;u32 u;}v;v.f=f;u32 u=v.u;return (u16)((u+0x7FFFu+((u>>16)&1u))>>16);}
__device__ __forceinline__ float sigf(float x){return 1.0f/(1.0f+__expf(-x));}
__device__ __forceinline__ float tanhf_(float x){return 1.0f-2.0f/(__expf(2.0f*x)+1.0f);}

__device__ __forceinline__ s16x8 pack8v(float4 a, float4 b){
  s16x8 r;
  r[0]=(short)f2bf(a.x); r[1]=(short)f2bf(a.y); r[2]=(short)f2bf(a.z); r[3]=(short)f2bf(a.w);
  r[4]=(short)f2bf(b.x); r[5]=(short)f2bf(b.y); r[6]=(short)f2bf(b.z); r[7]=(short)f2bf(b.w);
  return r;
}
__device__ __forceinline__ s16x8 pack8(const float* s){
  return pack8v(*(const float4*)s, *(const float4*)(s+4));
}
// 16B write-through store (bypasses L2 -> coherent at IF$)
__device__ __forceinline__ void st16_coh(u16* addr, s16x8 v){
  asm volatile("global_store_dwordx4 %0, %1, off sc0 sc1" :: "v"(addr), "v"(v) : "memory");
}
// poll group counter until >= target
__device__ __forceinline__ void poll_ctr(u32* ctr, u32 target, int wid, int lane){
  if (wid == 0 && lane == 0) {
    while (__hip_atomic_load(ctr, __ATOMIC_RELAXED, __HIP_MEMORY_SCOPE_AGENT) < target)
      __builtin_amdgcn_s_sleep(1);
  }
  asm volatile("" ::: "memory");
  __syncthreads();
}

// Persistent kernel: 512 blocks = 4 path-groups x 128 unit-blocks (8 units x 4 gates).
// 2 blocks/CU (VGPR<=256) -> 2 waves/SIMD for latency hiding.
__global__ void __launch_bounds__(256, 2)
tagger_net(const int* __restrict__ paths, const int* __restrict__ lengths,
           const float* __restrict__ emb,
           const float* __restrict__ Wih, const float* __restrict__ Whh,
           const float* __restrict__ bih, const float* __restrict__ bhh,
           const float* __restrict__ Win, const float* __restrict__ bin,
           const float* __restrict__ Wout, const float* __restrict__ bout,
           const float* __restrict__ Wlin, const float* __restrict__ blin,
           u16* __restrict__ X, u16* __restrict__ Hbuf,
           u16* __restrict__ vbuf, float* __restrict__ pmax,
           u32* ctrs, float* __restrict__ out)
{
  __shared__ __align__(16) float S[8192];    // 32 KB (2 blocks/CU -> 64 KB)
  const int tid  = threadIdx.x;
  const int wid  = tid >> 6, lane = tid & 63;
  const int lrow = lane & 15, lgrp = lane >> 4;
  const int bid  = blockIdx.x;
  const int g = bid >> 7, jb2 = bid & 127;
  const int p0 = g * 64, j0 = jb2 * 8;
  u32* ctr = ctrs + g * 64;

  // ---- init: gather ONE row of X[jb2>>6]; zero own Hbuf[0] chunk ----
  if (wid == 0) {
    int t0 = jb2 >> 6, row = jb2 & 63;
    int tok = paths[(p0 + row) * L_ + t0];
    const float* s = emb + (size_t)tok * IDIM + lane * 8;
    st16_coh(X + ((size_t)t0 * P_ + p0 + row) * IDIM + lane * 8,
             pack8v(*(const float4*)s, *(const float4*)(s + 4)));
  }
  {
    int row = tid >> 2, cp = (tid & 3) * 2;
    __hip_atomic_store((u32*)&Hbuf[(size_t)(p0 + row) * H_ + j0 + cp], 0u,
                       __ATOMIC_RELAXED, __HIP_MEMORY_SCOPE_AGENT);
  }
  __syncthreads();
  if (tid == 0) __hip_atomic_fetch_add(ctr, 1u, __ATOMIC_RELAXED, __HIP_MEMORY_SCOPE_AGENT);

  // ---- weights into registers: wave wid owns K chunks c = wid + 4*i (i=0..11) ----
  s16x8 breg[12][2];
#pragma unroll
  for (int i = 0; i < 12; ++i) {
    const int k = (wid + 4 * i) * 32 + lgrp * 8;
#pragma unroll
    for (int fn = 0; fn < 2; ++fn) {
      const int n = (fn * 2 + (lrow >> 3)) * H_ + j0 + (lrow & 7);
      const float* src = (k < IDIM) ? (Wih + (size_t)n * IDIM + k)
                                    : (Whh + (size_t)n * H_ + (k - IDIM));
      breg[i][fn] = pack8(src);
    }
  }

  const int prow = p0 + wid * 16 + lgrp * 4;
  int lenr[4];
#pragma unroll
  for (int r = 0; r < 4; ++r) lenr[r] = lengths[prow + r];
  const int ju = j0 + (lrow & 7);
  const float bias_i = bih[ju] + bhh[ju];
  const float bias_f = bih[H_ + ju] + bhh[H_ + ju];
  const float bias_g = bih[2 * H_ + ju] + bhh[2 * H_ + ju];
  const float bias_o = bih[3 * H_ + ju] + bhh[3 * H_ + ju];
  float cst[4] = {0.f,0.f,0.f,0.f}, hst[4] = {0.f,0.f,0.f,0.f};

  const size_t aX = (size_t)(p0 + lrow) * IDIM + lgrp * 8;
  const size_t aH = (size_t)(p0 + lrow) * H_   + lgrp * 8;

  poll_ctr(ctr, 128u, wid, lane);            // init done (X[0],X[1] + H0)

#define MM(FR, I0) do { \
    _Pragma("unroll") \
    for (int j_ = 0; j_ < 2; ++j_) \
      _Pragma("unroll") \
      for (int fm_ = 0; fm_ < 4; ++fm_) \
        _Pragma("unroll") \
        for (int fn_ = 0; fn_ < 2; ++fn_) \
          acc[fm_][fn_] = __builtin_amdgcn_mfma_f32_16x16x32_bf16(FR[j_][fm_], breg[(I0)+j_][fn_], acc[fm_][fn_], 0, 0, 0); \
  } while (0)

#define LDX2(DST, T, C0) do { \
    const u16* Xt_ = X + (size_t)(T) * (P_ * IDIM) + aX; \
    _Pragma("unroll") \
    for (int j_ = 0; j_ < 2; ++j_) { \
      const int k0_ = (wid + 4 * ((C0) + j_)) * 32; \
      _Pragma("unroll") \
      for (int fm_ = 0; fm_ < 4; ++fm_) \
        DST[j_][fm_] = *(const s16x8*)(Xt_ + (size_t)fm_ * (16 * IDIM) + k0_); \
    } } while (0)

#define LDH2(DST, C0) do { \
    _Pragma("unroll") \
    for (int j_ = 0; j_ < 2; ++j_) { \
      const int kh_ = wid * 32 + ((C0) + j_) * 128; \
      _Pragma("unroll") \
      for (int fm_ = 0; fm_ < 4; ++fm_) \
        DST[j_][fm_] = *(const s16x8*)(Hp + (size_t)fm_ * (16 * H_) + kh_); \
    } } while (0)

  s16x8 fx[2][4];
  LDX2(fx, 0, 0);                            // chunks 0,1 of step 0

  for (int t = 0; t < L_; ++t) {
    u16* Hw = Hbuf + (size_t)(t + 1) * PH;

    // progressive gather of X[t+2] (one row per gathering block), hidden under poll
    if (wid == 0 && jb2 < 64 && t + 2 < L_) {
      int tok = paths[(p0 + jb2) * L_ + (t + 2)];
      const float* s = emb + (size_t)tok * IDIM + lane * 8;
      st16_coh(X + ((size_t)(t + 2) * P_ + p0 + jb2) * IDIM + lane * 8,
               pack8v(*(const float4*)s, *(const float4*)(s + 4)));
    }
    // prefetch X chunks 2,3 of this step (ready: gathered >=2 steps ago)
    s16x8 fx2[2][4];
    LDX2(fx2, t, 2);

    poll_ctr(ctr, 128u * (u32)(t + 1), wid, lane);

    f32x4 acc[4][2];
#pragma unroll
    for (int a = 0; a < 4; ++a)
#pragma unroll
      for (int b = 0; b < 2; ++b)
#pragma unroll
        for (int e = 0; e < 4; ++e) acc[a][b][e] = 0.0f;

    const u16* Hp = Hbuf + (size_t)t * PH + aH;
    s16x8 fhA[2][4], fhB[2][4], fhC[2][4], fhD[2][4];
    LDH2(fhA, 0); LDH2(fhB, 2);              // issue first 4 H chunks
    MM(fx, 0);                               // X chunks 0,1 (regs ready)
    MM(fx2, 2);                              // X chunks 2,3
    MM(fhA, 4);  LDH2(fhC, 4);               // consume A, issue next
    MM(fhB, 6);  LDH2(fhD, 6);
    MM(fhC, 8);
    { const int tn = (t + 1 < L_) ? t + 1 : t; LDX2(fx, tn, 0); }  // prefetch next X
    MM(fhD, 10);

    // ---- cross-wave K-reduction (32 KB LDS) ----
#pragma unroll
    for (int fm = 0; fm < 4; ++fm)
#pragma unroll
      for (int fn = 0; fn < 2; ++fn)
        *(f32x4*)&S[((wid * 8) + fm * 2 + fn) * 256 + lane * 4] = acc[fm][fn];
    __syncthreads();
    f32x4 red[2];
#pragma unroll
    for (int fn = 0; fn < 2; ++fn) {
      red[fn] = *(const f32x4*)&S[(wid * 2 + fn) * 256 + lane * 4];
#pragma unroll
      for (int w = 1; w < 4; ++w)
        red[fn] += *(const f32x4*)&S[(w * 8 + wid * 2 + fn) * 256 + lane * 4];
    }

    // ---- gate exchange + LSTM epilogue ----
    // lanes lrow<8 hold (i,g); lanes lrow>=8 hold (f,o); swap via shfl_xor(8)
    const bool low = (lrow < 8);
#pragma unroll
    for (int r = 0; r < 4; ++r) {
      float o0 = __shfl_xor(red[0][r], 8);
      float o1 = __shfl_xor(red[1][r], 8);
      float gi = (low ? red[0][r] : o0) + bias_i;
      float gf = (low ? o0 : red[0][r]) + bias_f;
      float gg = (low ? red[1][r] : o1) + bias_g;
      float go = (low ? o1 : red[1][r]) + bias_o;
      if (t < lenr[r]) {
        float cn = sigf(gf) * cst[r] + sigf(gi) * tanhf_(gg);
        cst[r] = cn;
        hst[r] = sigf(go) * tanhf_(cn);
      }
      // paired u16 store: lanes (even u, odd u+1) pack one u32
      u32 b = (u32)f2bf(hst[r]);
      u32 oth = __shfl_xor(b, 1);
      if (low && (lane & 1) == 0)
        __hip_atomic_store((u32*)&Hw[(size_t)(prow + r) * H_ + j0 + lrow], b | (oth << 16),
                           __ATOMIC_RELAXED, __HIP_MEMORY_SCOPE_AGENT);
    }
    __syncthreads();                         // drain stores (barrier waits vmcnt)
    if (tid == 0) __hip_atomic_fetch_add(ctr, 1u, __ATOMIC_RELAXED, __HIP_MEMORY_SCOPE_AGENT);
  }

  // ================= tail =================
  poll_ctr(ctr, 128u * 65u, wid, lane);
  const u16* hfin = Hbuf + (size_t)L_ * PH;

  // ---- v = h@Wv^T + bv  (8 cols per block; frag cols 8..15 duplicate 0..7) ----
  {
    f32x4 a2[4];
#pragma unroll
    for (int a = 0; a < 4; ++a)
#pragma unroll
      for (int e = 0; e < 4; ++e) a2[a][e] = 0.0f;
    const u16* hp = hfin + aH;
    const float* wv = Win + (size_t)(2 * H_ + ju) * H_;
#pragma unroll
    for (int ic = 0; ic < 8; ++ic) {
      const int k0 = wid * 256 + ic * 32;
      s16x8 fb = pack8(wv + k0 + lgrp * 8);
#pragma unroll
      for (int fm = 0; fm < 4; ++fm) {
        s16x8 fa = *(const s16x8*)(hp + (size_t)fm * (16 * H_) + k0);
        a2[fm] = __builtin_amdgcn_mfma_f32_16x16x32_bf16(fa, fb, a2[fm], 0, 0, 0);
      }
    }
#pragma unroll
    for (int fm = 0; fm < 4; ++fm)
      *(f32x4*)&S[(wid * 4 + fm) * 256 + lane * 4] = a2[fm];
    __syncthreads();
    f32x4 rv = *(const f32x4*)&S[(wid) * 256 + lane * 4];
#pragma unroll
    for (int w = 1; w < 4; ++w)
      rv += *(const f32x4*)&S[(w * 4 + wid) * 256 + lane * 4];
    const float bvj = bin[2 * H_ + ju];
#pragma unroll
    for (int r = 0; r < 4; ++r) {
      u32 b = (u32)f2bf(rv[r] + bvj);
      u32 oth = __shfl_xor(b, 1);
      if (lrow < 8 && (lane & 1) == 0)
        __hip_atomic_store((u32*)&vbuf[(size_t)(prow + r) * H_ + j0 + lrow], b | (oth << 16),
                           __ATOMIC_RELAXED, __HIP_MEMORY_SCOPE_AGENT);
    }
  }
  __syncthreads();
  if (tid == 0) __hip_atomic_fetch_add(ctr, 1u, __ATOMIC_RELAXED, __HIP_MEMORY_SCOPE_AGENT);
  poll_ctr(ctr, 128u * 66u, wid, lane);

  // ---- attn = v@Wout^T (+bout), per-block max over 64 rows ----
  {
    f32x4 a2[4];
#pragma unroll
    for (int a = 0; a < 4; ++a)
#pragma unroll
      for (int e = 0; e < 4; ++e) a2[a][e] = 0.0f;
    const u16* vp = vbuf + aH;
    const float* wo = Wout + (size_t)ju * H_;
#pragma unroll
    for (int ic = 0; ic < 8; ++ic) {
      const int k0 = wid * 256 + ic * 32;
      s16x8 fb = pack8(wo + k0 + lgrp * 8);
#pragma unroll
      for (int fm = 0; fm < 4; ++fm) {
        s16x8 fa = *(const s16x8*)(vp + (size_t)fm * (16 * H_) + k0);
        a2[fm] = __builtin_amdgcn_mfma_f32_16x16x32_bf16(fa, fb, a2[fm], 0, 0, 0);
      }
    }
#pragma unroll
    for (int fm = 0; fm < 4; ++fm)
      *(f32x4*)&S[(wid * 4 + fm) * 256 + lane * 4] = a2[fm];
    __syncthreads();
    f32x4 rv = *(const f32x4*)&S[(wid) * 256 + lane * 4];
#pragma unroll
    for (int w = 1; w < 4; ++w)
      rv += *(const f32x4*)&S[(w * 4 + wid) * 256 + lane * 4];
    float m = fmaxf(fmaxf(rv[0], rv[1]), fmaxf(rv[2], rv[3])) + bout[ju];
    __syncthreads();
    S[(wid * 4 + lgrp) * 8 + (lrow & 7)] = m;   // dup lanes write same value
    __syncthreads();
    if (tid < 8) {
      float mx = S[tid];
#pragma unroll
      for (int s2 = 1; s2 < 16; ++s2) mx = fmaxf(mx, S[s2 * 8 + tid]);
      __hip_atomic_store(&pmax[(size_t)g * H_ + j0 + tid], mx,
                         __ATOMIC_RELAXED, __HIP_MEMORY_SCOPE_AGENT);
    }
  }
  __syncthreads();
  if (tid == 0) __hip_atomic_fetch_add(ctr, 1u, __ATOMIC_RELAXED, __HIP_MEMORY_SCOPE_AGENT);

  if (bid != 0) return;

  // ---- final: max over groups, 1024->2 dot, sigmoid ----
  if (wid == 0 && lane == 0) {
    for (int g2 = 0; g2 < 4; ++g2)
      while (__hip_atomic_load(ctrs + g2 * 64, __ATOMIC_RELAXED, __HIP_MEMORY_SCOPE_AGENT) < 128u * 67u)
        __builtin_amdgcn_s_sleep(1);
  }
  asm volatile("" ::: "memory");
  __syncthreads();
  {
    int j4 = tid * 4;
    float s0 = 0.f, s1 = 0.f;
#pragma unroll
    for (int e = 0; e < 4; ++e) {
      float pv = pmax[j4 + e];
#pragma unroll
      for (int gg2 = 1; gg2 < 4; ++gg2) pv = fmaxf(pv, pmax[gg2 * H_ + j4 + e]);
      s0 += pv * Wlin[j4 + e];
      s1 += pv * Wlin[H_ + j4 + e];
    }
    S[tid] = s0; S[256 + tid] = s1;
    __syncthreads();
    for (int s2 = 128; s2 > 0; s2 >>= 1) {
      if (tid < s2) { S[tid] += S[tid + s2]; S[256 + tid] += S[256 + tid + s2]; }
      __syncthreads();
    }
    if (tid == 0) {
      out[0] = sigf(S[0] + blin[0]);
      out[1] = sigf(S[256] + blin[1]);
    }
  }
}

extern "C" void kernel_launch(void* const* d_in, const int* in_sizes, int n_in,
                              void* d_out, int out_size, void* d_ws, size_t ws_size,
                              hipStream_t stream) {
  const int*   paths   = (const int*)d_in[0];
  const int*   lengths = (const int*)d_in[1];
  const float* emb     = (const float*)d_in[2];
  const float* Wih     = (const float*)d_in[3];
  const float* Whh     = (const float*)d_in[4];
  const float* bih     = (const float*)d_in[5];
  const float* bhh     = (const float*)d_in[6];
  const float* Win     = (const float*)d_in[7];
  const float* bin     = (const float*)d_in[8];
  const float* Wout    = (const float*)d_in[9];
  const float* bout    = (const float*)d_in[10];
  const float* Wlin    = (const float*)d_in[11];
  const float* blin    = (const float*)d_in[12];
  float* out = (float*)d_out;

  char* ws = (char*)d_ws;
  u32*   ctrs   = (u32*)  (ws);                  //      1,024 (4 ctrs, 256B apart)
  float* pmax   = (float*)(ws + 4096);           //     16,384
  u16*   X      = (u16*)  (ws + 32768);          // 16,777,216
  u16*   Hbuf   = (u16*)  (ws + 16810240);       // 65 x 524,288 = 34,078,720
  u16*   vbuf   = (u16*)  (ws + 50888960);       //    524,288   (total ~51.4 MB)

  hipMemsetAsync(ctrs, 0, 1024, stream);
  tagger_net<<<512, 256, 0, stream>>>(paths, lengths, emb, Wih, Whh, bih, bhh,
                                      Win, bin, Wout, bout, Wlin, blin,
                                      X, Hbuf, vbuf, pmax, ctrs, out);
}

// Round 6
// 632.064 us; speedup vs baseline: 1.6954x; 1.6954x over previous
//
#include <hip/hip_runtime.h>
#include <stdint.h>

typedef unsigned short u16;
typedef unsigned int u32;
typedef __attribute__((ext_vector_type(8))) short s16x8;
typedef __attribute__((ext_vector_type(4))) float f32x4;

#define P_ 256
#define L_ 64
#define IDIM 512
#define H_ 1024
#define PH (P_ * H_)

__device__ __forceinline__ u16 f2bf(float f){union{float f;u32 u;}v;v.f=f;u32 u=v.u;return (u16)((u+0x7FFFu+((u>>16)&1u))>>16);}
__device__ __forceinline__ float sigf(float x){return 1.0f/(1.0f+__expf(-x));}
__device__ __forceinline__ float tanhf_(float x){return 1.0f-2.0f/(__expf(2.0f*x)+1.0f);}

__device__ __forceinline__ s16x8 pack8v(float4 a, float4 b){
  s16x8 r;
  r[0]=(short)f2bf(a.x); r[1]=(short)f2bf(a.y); r[2]=(short)f2bf(a.z); r[3]=(short)f2bf(a.w);
  r[4]=(short)f2bf(b.x); r[5]=(short)f2bf(b.y); r[6]=(short)f2bf(b.z); r[7]=(short)f2bf(b.w);
  return r;
}
__device__ __forceinline__ s16x8 pack8(const float* s){
  return pack8v(*(const float4*)s, *(const float4*)(s+4));
}
// 16B write-through store (bypasses L2 -> coherent at IF$)
__device__ __forceinline__ void st16_coh(u16* addr, s16x8 v){
  asm volatile("global_store_dwordx4 %0, %1, off sc0 sc1" :: "v"(addr), "v"(v) : "memory");
}
// paired 2-lane bf16 -> one 32-bit write-through store
__device__ __forceinline__ void st_pair(u16* addr, float hv, int lane){
  u32 b = (u32)f2bf(hv);
  u32 other = __shfl_xor(b, 1);
  if ((lane & 1) == 0) {
    u32 w = b | (other << 16);
    __hip_atomic_store((u32*)addr, w, __ATOMIC_RELAXED, __HIP_MEMORY_SCOPE_AGENT);
  }
}
__device__ __forceinline__ void set_flag(u32* f, u32 v){
  __hip_atomic_store(f, v, __ATOMIC_RELAXED, __HIP_MEMORY_SCOPE_AGENT);
}
// wave0: lane l polls flag[l] of own group (one coalesced 256B load / iter, NO RMW)
__device__ __forceinline__ void poll_flags(u32* fg, u32 target, int wid, int lane){
  if (wid == 0) {
    for (;;) {
      u32 f = __hip_atomic_load(&fg[lane], __ATOMIC_RELAXED, __HIP_MEMORY_SCOPE_AGENT);
      if (__all((int)(f >= target))) break;
      __builtin_amdgcn_s_sleep(1);
    }
  }
  asm volatile("" ::: "memory");
  __syncthreads();
}

// Persistent kernel: 256 blocks = 4 path-groups x 64 unit-blocks (16 units x 4 gates).
// H renamed per step (Hbuf[t]); sync = versioned per-block flags (no atomics RMW).
__global__ void __launch_bounds__(256, 1)
tagger_net(const int* __restrict__ paths, const int* __restrict__ lengths,
           const float* __restrict__ emb,
           const float* __restrict__ Wih, const float* __restrict__ Whh,
           const float* __restrict__ bih, const float* __restrict__ bhh,
           const float* __restrict__ Win, const float* __restrict__ bin,
           const float* __restrict__ Wout, const float* __restrict__ bout,
           const float* __restrict__ Wlin, const float* __restrict__ blin,
           u16* __restrict__ X, u16* __restrict__ Hbuf,
           u16* __restrict__ vbuf, float* __restrict__ pmax,
           u32* flags, float* __restrict__ out)
{
  __shared__ __align__(16) float S[16384];   // 64 KB K-reduction scratch
  const int tid  = threadIdx.x;
  const int wid  = tid >> 6, lane = tid & 63;
  const int lrow = lane & 15, lgrp = lane >> 4;
  const int bid  = blockIdx.x;
  const int g = bid >> 6, jb = bid & 63;
  const int p0 = g * 64, j0 = jb * 16;
  u32* fgrp = flags + g * 64;                // this group's 64 flags (256B)
  u32* myflag = fgrp + jb;

  // ---- init: gather X[t=jb][p0..p0+63][:] (write-through), zero own Hbuf[0] chunk
  for (int it = 0; it < 16; ++it) {
    int e = (it * 256 + tid) * 8;
    int row = e >> 9, col = e & 511;
    int tok = paths[(p0 + row) * L_ + jb];
    const float* s = emb + (size_t)tok * IDIM + col;
    float4 a = *(const float4*)s, b4 = *(const float4*)(s + 4);
    st16_coh(X + ((size_t)jb * P_ + p0 + row) * IDIM + col, pack8v(a, b4));
  }
#pragma unroll
  for (int i = 0; i < 2; ++i) {
    int idx = tid * 2 + i;                    // 512 u32 cells: 64 rows x 8 col-pairs
    int row = idx >> 3, cp = idx & 7;
    __hip_atomic_store((u32*)&Hbuf[(size_t)(p0 + row) * H_ + j0 + cp * 2], 0u,
                       __ATOMIC_RELAXED, __HIP_MEMORY_SCOPE_AGENT);
  }
  __syncthreads();                            // drains vmcnt of all waves
  if (tid == 0) set_flag(myflag, 1u);

  // ---- weights into registers: wave wid owns K chunks c = wid + 4*i ----
  s16x8 breg[12][4];
#pragma unroll
  for (int i = 0; i < 12; ++i) {
    const int k = (wid + 4 * i) * 32 + lgrp * 8;
#pragma unroll
    for (int fn = 0; fn < 4; ++fn) {
      const int n = fn * H_ + j0 + lrow;
      const float* src = (k < IDIM) ? (Wih + (size_t)n * IDIM + k)
                                    : (Whh + (size_t)n * H_ + (k - IDIM));
      breg[i][fn] = pack8(src);
    }
  }

  const int prow = p0 + wid * 16 + lgrp * 4;
  int lenr[4]; float biasv[4];
#pragma unroll
  for (int r2 = 0; r2 < 4; ++r2) lenr[r2] = lengths[prow + r2];
#pragma unroll
  for (int fn = 0; fn < 4; ++fn) {
    int n = fn * H_ + j0 + lrow;
    biasv[fn] = bih[n] + bhh[n];
  }
  float cst[4] = {0.f,0.f,0.f,0.f}, hst[4] = {0.f,0.f,0.f,0.f};

  poll_flags(fgrp, 1u, wid, lane);            // init done (own group)

  const size_t aX = (size_t)(p0 + lrow) * IDIM + lgrp * 8;
  const size_t aH = (size_t)(p0 + lrow) * H_   + lgrp * 8;

  s16x8 fx[4][4];
#define LOADX(T) do { \
    const u16* Xt_ = X + (size_t)(T) * (P_ * IDIM) + aX; \
    _Pragma("unroll") \
    for (int i_ = 0; i_ < 4; ++i_) { \
      const int k0_ = wid * 32 + i_ * 128; \
      _Pragma("unroll") \
      for (int fm_ = 0; fm_ < 4; ++fm_) \
        fx[i_][fm_] = *(const s16x8*)(Xt_ + (size_t)fm_ * (16 * IDIM) + k0_); \
    } } while (0)

  LOADX(0);

  for (int t = 0; t < L_; ++t) {
    const u16* Hr = Hbuf + (size_t)t * PH;
    u16*       Hw = Hbuf + (size_t)(t + 1) * PH;

    f32x4 acc[4][4];
#pragma unroll
    for (int a = 0; a < 4; ++a)
#pragma unroll
      for (int b = 0; b < 4; ++b)
#pragma unroll
        for (int e = 0; e < 4; ++e) acc[a][b][e] = 0.0f;

    // ---- X phase (independent of other blocks, hides poll) ----
#pragma unroll
    for (int i = 0; i < 4; ++i)
#pragma unroll
      for (int fm = 0; fm < 4; ++fm)
#pragma unroll
        for (int fn = 0; fn < 4; ++fn)
          acc[fm][fn] = __builtin_amdgcn_mfma_f32_16x16x32_bf16(fx[i][fm], breg[i][fn], acc[fm][fn], 0, 0, 0);

    // ---- wait for Hbuf[t] complete (64 sibling blocks) ----
    poll_flags(fgrp, (u32)(t + 1), wid, lane);

    // ---- H phase: plain cached loads (addresses never stale: write-once rename) ----
    const u16* Hp = Hr + aH;
#pragma unroll
    for (int half = 0; half < 2; ++half) {
      s16x8 fh[4][4];
#pragma unroll
      for (int i = 0; i < 4; ++i) {
        const int kh = wid * 32 + (half * 4 + i) * 128;
#pragma unroll
        for (int fm = 0; fm < 4; ++fm)
          fh[i][fm] = *(const s16x8*)(Hp + (size_t)fm * (16 * H_) + kh);
      }
#pragma unroll
      for (int i = 0; i < 4; ++i)
#pragma unroll
        for (int fm = 0; fm < 4; ++fm)
#pragma unroll
          for (int fn = 0; fn < 4; ++fn)
            acc[fm][fn] = __builtin_amdgcn_mfma_f32_16x16x32_bf16(fh[i][fm], breg[4 + half * 4 + i][fn], acc[fm][fn], 0, 0, 0);
    }

    const int tp1 = (t < L_ - 1) ? (t + 1) : (L_ - 1);
    LOADX(tp1);                               // prefetch next X under epilogue

    // ---- cross-wave K-reduction ----
#pragma unroll
    for (int fm = 0; fm < 4; ++fm)
#pragma unroll
      for (int fn = 0; fn < 4; ++fn)
        *(f32x4*)&S[((wid * 16) + fm * 4 + fn) * 256 + lane * 4] = acc[fm][fn];
    __syncthreads();
    f32x4 red[4];
#pragma unroll
    for (int fn = 0; fn < 4; ++fn) {
      red[fn] = *(const f32x4*)&S[(wid * 4 + fn) * 256 + lane * 4];
#pragma unroll
      for (int w = 1; w < 4; ++w)
        red[fn] += *(const f32x4*)&S[(w * 16 + wid * 4 + fn) * 256 + lane * 4];
    }

    // ---- in-register gate epilogue, write-through H ----
#pragma unroll
    for (int r2 = 0; r2 < 4; ++r2) {
      if (t < lenr[r2]) {
        float gi = red[0][r2] + biasv[0];
        float gf = red[1][r2] + biasv[1];
        float gg = red[2][r2] + biasv[2];
        float go = red[3][r2] + biasv[3];
        float cn = sigf(gf) * cst[r2] + sigf(gi) * tanhf_(gg);
        cst[r2] = cn;
        hst[r2] = sigf(go) * tanhf_(cn);
      }
      st_pair(&Hw[(size_t)(prow + r2) * H_ + j0 + lrow], hst[r2], lane);
    }
    __syncthreads();                          // drain stores (all waves)
    if (tid == 0) set_flag(myflag, (u32)(t + 2));
  }

  // ================= tail =================
  const u16* hfin = Hbuf + (size_t)L_ * PH;
  poll_flags(fgrp, 65u, wid, lane);

  // ---- v = h@Wv^T + bv ----
  {
    f32x4 acc2[4];
#pragma unroll
    for (int a = 0; a < 4; ++a)
#pragma unroll
      for (int e = 0; e < 4; ++e) acc2[a][e] = 0.0f;
    const u16* hp = hfin + aH;
    const float* wv = Win + (size_t)(2 * H_ + j0 + lrow) * H_;
#pragma unroll
    for (int ic = 0; ic < 8; ++ic) {
      const int k0 = wid * 256 + ic * 32;
      s16x8 fbv = pack8(wv + k0 + lgrp * 8);
#pragma unroll
      for (int fm = 0; fm < 4; ++fm) {
        s16x8 fav = *(const s16x8*)(hp + (size_t)fm * (16 * H_) + k0);
        acc2[fm] = __builtin_amdgcn_mfma_f32_16x16x32_bf16(fav, fbv, acc2[fm], 0, 0, 0);
      }
    }
#pragma unroll
    for (int fm = 0; fm < 4; ++fm)
      *(f32x4*)&S[(wid * 4 + fm) * 256 + lane * 4] = acc2[fm];
    __syncthreads();
    f32x4 rv = *(const f32x4*)&S[(wid) * 256 + lane * 4];
#pragma unroll
    for (int w = 1; w < 4; ++w)
      rv += *(const f32x4*)&S[(w * 4 + wid) * 256 + lane * 4];
    float bvj = bin[2 * H_ + j0 + lrow];
#pragma unroll
    for (int r2 = 0; r2 < 4; ++r2)
      st_pair(&vbuf[(size_t)(prow + r2) * H_ + j0 + lrow], rv[r2] + bvj, lane);
  }
  __syncthreads();
  if (tid == 0) set_flag(myflag, 66u);
  poll_flags(fgrp, 66u, wid, lane);

  // ---- attn = v@Wout^T + bout, then per-block max over own 64 rows ----
  {
    f32x4 acc2[4];
#pragma unroll
    for (int a = 0; a < 4; ++a)
#pragma unroll
      for (int e = 0; e < 4; ++e) acc2[a][e] = 0.0f;
    const u16* vp = vbuf + aH;
    const float* wo = Wout + (size_t)(j0 + lrow) * H_;
#pragma unroll
    for (int ic = 0; ic < 8; ++ic) {
      const int k0 = wid * 256 + ic * 32;
      s16x8 fbv = pack8(wo + k0 + lgrp * 8);
#pragma unroll
      for (int fm = 0; fm < 4; ++fm) {
        s16x8 fav = *(const s16x8*)(vp + (size_t)fm * (16 * H_) + k0);
        acc2[fm] = __builtin_amdgcn_mfma_f32_16x16x32_bf16(fav, fbv, acc2[fm], 0, 0, 0);
      }
    }
#pragma unroll
    for (int fm = 0; fm < 4; ++fm)
      *(f32x4*)&S[(wid * 4 + fm) * 256 + lane * 4] = acc2[fm];
    __syncthreads();
    f32x4 rv = *(const f32x4*)&S[(wid) * 256 + lane * 4];
#pragma unroll
    for (int w = 1; w < 4; ++w)
      rv += *(const f32x4*)&S[(w * 4 + wid) * 256 + lane * 4];
    float bo = bout[j0 + lrow];
    float m = fmaxf(fmaxf(rv[0], rv[1]), fmaxf(rv[2], rv[3])) + bo;
    __syncthreads();
    S[(wid * 4 + lgrp) * 16 + lrow] = m;
    __syncthreads();
    if (tid < 16) {
      float mx = S[tid];
#pragma unroll
      for (int s2 = 1; s2 < 16; ++s2) mx = fmaxf(mx, S[s2 * 16 + tid]);
      __hip_atomic_store(&pmax[(size_t)g * H_ + j0 + tid], mx, __ATOMIC_RELAXED, __HIP_MEMORY_SCOPE_AGENT);
    }
  }
  __syncthreads();
  if (tid == 0) set_flag(myflag, 67u);

  if (bid != 0) return;

  // ---- final: max over groups, 1024->2 dot, sigmoid ----
  if (wid == 0) {
    for (int g2 = 0; g2 < 4; ++g2) {
      for (;;) {
        u32 f = __hip_atomic_load(&flags[g2 * 64 + lane], __ATOMIC_RELAXED, __HIP_MEMORY_SCOPE_AGENT);
        if (__all((int)(f >= 67u))) break;
        __builtin_amdgcn_s_sleep(1);
      }
    }
  }
  asm volatile("" ::: "memory");
  __syncthreads();
  {
    int j4 = tid * 4;
    float s0 = 0.f, s1 = 0.f;
#pragma unroll
    for (int e = 0; e < 4; ++e) {
      float pv = pmax[j4 + e];
#pragma unroll
      for (int gg2 = 1; gg2 < 4; ++gg2) pv = fmaxf(pv, pmax[gg2 * H_ + j4 + e]);
      s0 += pv * Wlin[j4 + e];
      s1 += pv * Wlin[H_ + j4 + e];
    }
    S[tid] = s0; S[256 + tid] = s1;
    __syncthreads();
    for (int s2 = 128; s2 > 0; s2 >>= 1) {
      if (tid < s2) { S[tid] += S[tid + s2]; S[256 + tid] += S[256 + tid + s2]; }
      __syncthreads();
    }
    if (tid == 0) {
      out[0] = sigf(S[0] + blin[0]);
      out[1] = sigf(S[256] + blin[1]);
    }
  }
}

extern "C" void kernel_launch(void* const* d_in, const int* in_sizes, int n_in,
                              void* d_out, int out_size, void* d_ws, size_t ws_size,
                              hipStream_t stream) {
  const int*   paths   = (const int*)d_in[0];
  const int*   lengths = (const int*)d_in[1];
  const float* emb     = (const float*)d_in[2];
  const float* Wih     = (const float*)d_in[3];
  const float* Whh     = (const float*)d_in[4];
  const float* bih     = (const float*)d_in[5];
  const float* bhh     = (const float*)d_in[6];
  const float* Win     = (const float*)d_in[7];
  const float* bin     = (const float*)d_in[8];
  const float* Wout    = (const float*)d_in[9];
  const float* bout    = (const float*)d_in[10];
  const float* Wlin    = (const float*)d_in[11];
  const float* blin    = (const float*)d_in[12];
  float* out = (float*)d_out;

  char* ws = (char*)d_ws;
  u32*   flags  = (u32*)  (ws);                  //      1,024 (256 u32; group g at +g*256B)
  float* pmax   = (float*)(ws + 4096);           //     16,384
  u16*   X      = (u16*)  (ws + 32768);          // 16,777,216
  u16*   Hbuf   = (u16*)  (ws + 16810240);       // 65 x 524,288 = 34,078,720
  u16*   vbuf   = (u16*)  (ws + 50888960);       //    524,288   (total ~51.4 MB)

  hipMemsetAsync(flags, 0, 1024, stream);
  tagger_net<<<256, 256, 0, stream>>>(paths, lengths, emb, Wih, Whh, bih, bhh,
                                      Win, bin, Wout, bout, Wlin, blin,
                                      X, Hbuf, vbuf, pmax, flags, out);
}